// Round 5
// baseline (945.016 us; speedup 1.0000x reference)
//
#include <hip/hip_runtime.h>
#include <math.h>

#define NPTS 8192
#define TPB  256          // threads per block, pair kernels
#define TPM  256          // threads per block, merge kernels

__device__ __forceinline__ float fmax3(float a, float b, float c) {
    return fmaxf(fmaxf(a, b), c);   // folds to v_max3_f32 (abs modifiers at leaves)
}

// Branchless sorted-descending top-4 insert (7 ops).
__device__ __forceinline__ void ins4(float d, float& t0, float& t1, float& t2, float& t3) {
    float n0 = fminf(t0, d);  t0 = fmaxf(t0, d);
    float n1 = fminf(t1, n0); t1 = fmaxf(t1, n0);
    float n2 = fminf(t2, n1); t2 = fmaxf(t2, n1);
    t3 = fmaxf(t3, n2);
}

__device__ double digamma_d(double x) {
    double r = 0.0;
    while (x < 6.0) { r -= 1.0 / x; x += 1.0; }
    double f = 1.0 / (x * x);
    double t = f * (1.0/12.0 - f * (1.0/120.0 - f * (1.0/252.0 - f * (1.0/240.0 - f * (1.0/132.0)))));
    return r + log(x) - 0.5 / x - t;
}

// Cooperative stage of TILE points (x:16 + y:16 floats) into LDS.
// Layout: pts4[pt*8 + c], c<4 = x float4s, c>=4 = y float4s.
template <int TILE>
__device__ __forceinline__ void stage_tile(
    float4* pts4, const float* __restrict__ x, const float* __restrict__ y, int jt)
{
    #pragma unroll
    for (int i = 0; i < (TILE * 8) / TPB; ++i) {
        int li = i * TPB + threadIdx.x;
        int pt = li >> 3, c = li & 7;
        const float4* src = (c < 4)
            ? reinterpret_cast<const float4*>(x) + (size_t)(jt + pt) * 4 + c
            : reinterpret_cast<const float4*>(y) + (size_t)(jt + pt) * 4 + (c - 4);
        pts4[li] = *src;
    }
}

__device__ __forceinline__ void load_query(float* qv, const float* __restrict__ x,
                                           const float* __restrict__ y, int q)
{
    const float4* qx4 = reinterpret_cast<const float4*>(x) + (size_t)q * 4;
    const float4* qy4 = reinterpret_cast<const float4*>(y) + (size_t)q * 4;
    #pragma unroll
    for (int i = 0; i < 4; ++i) {
        float4 v = qx4[i];
        qv[4*i+0] = v.x; qv[4*i+1] = v.y; qv[4*i+2] = v.z; qv[4*i+3] = v.w;
        float4 w = qy4[i];
        qv[16+4*i+0] = w.x; qv[16+4*i+1] = w.y; qv[16+4*i+2] = w.z; qv[16+4*i+3] = w.w;
    }
}

// ---------------------------------------------------------------------------
// K1: per-query partial top-4 of joint Chebyshev distance over a point split.
// grid = (NPTS/(TPB*QPL), S). QPL queries/lane amortize each LDS point read.
// Chunked point access keeps p's live range at 4 regs.
// ---------------------------------------------------------------------------
template <int QPL, int TILE>
__global__ __launch_bounds__(TPB, 2) void knn_part_kernel(
    const float* __restrict__ x, const float* __restrict__ y,
    float4* __restrict__ part, int pps)
{
    __shared__ float4 pts4[TILE * 8];
    float qv[QPL][32];
    float t0[QPL], t1[QPL], t2[QPL], t3[QPL];
    #pragma unroll
    for (int u = 0; u < QPL; ++u) {
        load_query(qv[u], x, y, blockIdx.x * (TPB * QPL) + threadIdx.x + u * TPB);
        t0[u] = t1[u] = t2[u] = t3[u] = -1.0f;
    }

    const int j0 = blockIdx.y * pps;
    for (int jt = j0; jt < j0 + pps; jt += TILE) {
        stage_tile<TILE>(pts4, x, y, jt);
        __syncthreads();
        #pragma unroll 2
        for (int jj = 0; jj < TILE; ++jj) {
            const float4* pj = &pts4[jj * 8];
            float m[QPL];
            #pragma unroll
            for (int u = 0; u < QPL; ++u) m[u] = 0.0f;   // distances >= 0
            #pragma unroll
            for (int i = 0; i < 8; ++i) {
                float4 v = pj[i];                         // wave-uniform broadcast
                #pragma unroll
                for (int u = 0; u < QPL; ++u) {
                    float d0 = qv[u][4*i+0] - v.x;
                    float d1 = qv[u][4*i+1] - v.y;
                    float d2 = qv[u][4*i+2] - v.z;
                    float d3 = qv[u][4*i+3] - v.w;
                    m[u] = fmax3(m[u], fmax3(fabsf(d0), fabsf(d1), fabsf(d2)), fabsf(d3));
                }
            }
            #pragma unroll
            for (int u = 0; u < QPL; ++u)
                ins4(m[u], t0[u], t1[u], t2[u], t3[u]);
        }
        __syncthreads();
    }
    #pragma unroll
    for (int u = 0; u < QPL; ++u) {
        int q = blockIdx.x * (TPB * QPL) + threadIdx.x + u * TPB;
        part[(size_t)blockIdx.y * NPTS + q] = make_float4(t0[u], t1[u], t2[u], t3[u]);
    }
}

// ---------------------------------------------------------------------------
// K2: merge S partial top-4 lists per query -> radius r[q]
// ---------------------------------------------------------------------------
__global__ __launch_bounds__(TPM) void knn_merge_kernel(
    const float4* __restrict__ part, float* __restrict__ r, int S)
{
    const int q = blockIdx.x * TPM + threadIdx.x;
    float t0=-1.f,t1=-1.f,t2=-1.f,t3=-1.f;
    for (int s = 0; s < S; ++s) {
        float4 v = part[(size_t)s * NPTS + q];
        ins4(v.x, t0, t1, t2, t3);
        ins4(v.y, t0, t1, t2, t3);
        ins4(v.z, t0, t1, t2, t3);
        ins4(v.w, t0, t1, t2, t3);
    }
    r[q] = t3 - 1e-15f;
}

// ---------------------------------------------------------------------------
// K3: partial inclusive range counts in X and Y marginals.
// ---------------------------------------------------------------------------
template <int QPL, int TILE>
__global__ __launch_bounds__(TPB, 2) void count_part_kernel(
    const float* __restrict__ x, const float* __restrict__ y,
    const float* __restrict__ r,
    unsigned short* __restrict__ cx, unsigned short* __restrict__ cy, int pps)
{
    __shared__ float4 pts4[TILE * 8];
    float qv[QPL][32];
    float rq[QPL];
    int nx[QPL], ny[QPL];
    #pragma unroll
    for (int u = 0; u < QPL; ++u) {
        int q = blockIdx.x * (TPB * QPL) + threadIdx.x + u * TPB;
        load_query(qv[u], x, y, q);
        rq[u] = r[q];
        nx[u] = ny[u] = 0;
    }

    const int j0 = blockIdx.y * pps;
    for (int jt = j0; jt < j0 + pps; jt += TILE) {
        stage_tile<TILE>(pts4, x, y, jt);
        __syncthreads();
        #pragma unroll 2
        for (int jj = 0; jj < TILE; ++jj) {
            const float4* pj = &pts4[jj * 8];
            float mx[QPL], my[QPL];
            #pragma unroll
            for (int u = 0; u < QPL; ++u) { mx[u] = 0.0f; my[u] = 0.0f; }
            #pragma unroll
            for (int i = 0; i < 8; ++i) {
                float4 v = pj[i];                         // wave-uniform broadcast
                #pragma unroll
                for (int u = 0; u < QPL; ++u) {
                    float d0 = qv[u][4*i+0] - v.x;
                    float d1 = qv[u][4*i+1] - v.y;
                    float d2 = qv[u][4*i+2] - v.z;
                    float d3 = qv[u][4*i+3] - v.w;
                    float t  = fmax3(fmax3(fabsf(d0), fabsf(d1), fabsf(d2)), fabsf(d3),
                                     (i < 4) ? mx[u] : my[u]);
                    if (i < 4) mx[u] = t; else my[u] = t;
                }
            }
            #pragma unroll
            for (int u = 0; u < QPL; ++u) {
                nx[u] += (mx[u] <= rq[u]) ? 1 : 0;
                ny[u] += (my[u] <= rq[u]) ? 1 : 0;
            }
        }
        __syncthreads();
    }
    #pragma unroll
    for (int u = 0; u < QPL; ++u) {
        int q = blockIdx.x * (TPB * QPL) + threadIdx.x + u * TPB;
        cx[(size_t)blockIdx.y * NPTS + q] = (unsigned short)nx[u];
        cy[(size_t)blockIdx.y * NPTS + q] = (unsigned short)ny[u];
    }
}

// ---------------------------------------------------------------------------
// K4: merge partial counts -> digamma(nx)+digamma(ny) per query (f64).
// ---------------------------------------------------------------------------
__global__ __launch_bounds__(TPM) void count_merge_kernel(
    const unsigned short* __restrict__ cx, const unsigned short* __restrict__ cy,
    double* __restrict__ dig, int S)
{
    const int q = blockIdx.x * TPM + threadIdx.x;
    int nx = 0, ny = 0;
    for (int s = 0; s < S; ++s) {
        nx += cx[(size_t)s * NPTS + q];
        ny += cy[(size_t)s * NPTS + q];
    }
    dig[q] = digamma_d((double)nx) + digamma_d((double)ny);
}

// ---------------------------------------------------------------------------
// K5: ans = psi(N) + psi(k) - mean(psi(nx)+psi(ny))
// (log/log2 terms of the reference cancel exactly in ans_x+ans_y-ans_xy)
// ---------------------------------------------------------------------------
__global__ __launch_bounds__(TPM) void final_kernel(
    const double* __restrict__ dig, float* __restrict__ out)
{
    __shared__ double sm[TPM];
    double s = 0.0;
    for (int i = threadIdx.x; i < NPTS; i += TPM) s += dig[i];
    sm[threadIdx.x] = s;
    __syncthreads();
    for (int w = TPM / 2; w > 0; w >>= 1) {
        if (threadIdx.x < w) sm[threadIdx.x] += sm[threadIdx.x + w];
        __syncthreads();
    }
    if (threadIdx.x == 0) {
        double ans = digamma_d((double)NPTS) + digamma_d(4.0) - sm[0] / (double)NPTS;
        out[0] = (float)ans;
    }
}

// ---------------------------------------------------------------------------
extern "C" void kernel_launch(void* const* d_in, const int* in_sizes, int n_in,
                              void* d_out, int out_size, void* d_ws, size_t ws_size,
                              hipStream_t stream)
{
    (void)in_sizes; (void)n_in; (void)out_size;
    const float* x = (const float*)d_in[0];
    const float* y = (const float*)d_in[1];
    float* out = (float*)d_out;

    // workspace: dig (NPTS f64) | r (NPTS f32) | part (Sk*NPTS float4) | cx,cy (Sc*NPTS u16 each)
    char* ws = (char*)d_ws;
    double* dig = (double*)ws;
    float*  r   = (float*)(ws + (size_t)NPTS * 8);
    char*   p0  = (char*)((((size_t)(ws + (size_t)NPTS * 12)) + 15) & ~(size_t)15);

    // asymmetric splits: knn partials are 16 B/entry, count partials 4 B/entry
    int Sk = 128, Sc = 256;
    auto need = [&](int sk, int sc) {
        return (size_t)(p0 - ws) + (size_t)sk * NPTS * 16 + (size_t)sc * NPTS * 4;
    };
    while (Sk > 32 && need(Sk, Sc) > ws_size) { Sk >>= 1; Sc >>= 1; }

    float4* part = (float4*)p0;
    unsigned short* cx = (unsigned short*)(p0 + (size_t)Sk * NPTS * 16);
    unsigned short* cy = cx + (size_t)Sc * NPTS;

    const int pps_k = NPTS / Sk;   // Sk<=128 -> >=64, multiple of 64
    const int pps_c = NPTS / Sc;   // Sc<=256 -> >=32, multiple of 32

    dim3 gridK(NPTS / (TPB * 4), Sk);
    dim3 gridC(NPTS / (TPB * 4), Sc);
    knn_part_kernel<4, 64><<<gridK, TPB, 0, stream>>>(x, y, part, pps_k);
    knn_merge_kernel<<<NPTS / TPM, TPM, 0, stream>>>(part, r, Sk);
    count_part_kernel<4, 32><<<gridC, TPB, 0, stream>>>(x, y, r, cx, cy, pps_c);
    count_merge_kernel<<<NPTS / TPM, TPM, 0, stream>>>(cx, cy, dig, Sc);
    final_kernel<<<1, TPM, 0, stream>>>(dig, out);
}

// Round 6
// 329.136 us; speedup vs baseline: 2.8712x; 2.8712x over previous
//
#include <hip/hip_runtime.h>
#include <math.h>

#define NPTS 8192
#define TPB  128          // threads per block, pair kernels
#define QPL  4            // queries per lane (512 queries per block)
#define TILE 64           // points staged per LDS tile (8 KB)
#define TPM  256          // threads per block, merge kernels

__device__ __forceinline__ float fmax3(float a, float b, float c) {
    return fmaxf(fmaxf(a, b), c);   // folds to v_max3_f32 (abs modifiers at leaves)
}

// Branchless sorted-descending top-4 insert (7 ops).
__device__ __forceinline__ void ins4(float d, float& t0, float& t1, float& t2, float& t3) {
    float n0 = fminf(t0, d);  t0 = fmaxf(t0, d);
    float n1 = fminf(t1, n0); t1 = fmaxf(t1, n0);
    float n2 = fminf(t2, n1); t2 = fmaxf(t2, n1);
    t3 = fmaxf(t3, n2);
}

__device__ double digamma_d(double x) {
    double r = 0.0;
    while (x < 6.0) { r -= 1.0 / x; x += 1.0; }
    double f = 1.0 / (x * x);
    double t = f * (1.0/12.0 - f * (1.0/120.0 - f * (1.0/252.0 - f * (1.0/240.0 - f * (1.0/132.0)))));
    return r + log(x) - 0.5 / x - t;
}

// Cooperative stage of TILE points (x:16 + y:16 floats) into LDS.
// Layout: pts4[pt*8 + c], c<4 = x float4s, c>=4 = y float4s.
__device__ __forceinline__ void stage_tile(
    float4* pts4, const float* __restrict__ x, const float* __restrict__ y, int jt)
{
    #pragma unroll
    for (int i = 0; i < (TILE * 8) / TPB; ++i) {
        int li = i * TPB + threadIdx.x;
        int pt = li >> 3, c = li & 7;
        const float4* src = (c < 4)
            ? reinterpret_cast<const float4*>(x) + (size_t)(jt + pt) * 4 + c
            : reinterpret_cast<const float4*>(y) + (size_t)(jt + pt) * 4 + (c - 4);
        pts4[li] = *src;
    }
}

__device__ __forceinline__ void load_query(float* qv, const float* __restrict__ x,
                                           const float* __restrict__ y, int q)
{
    const float4* qx4 = reinterpret_cast<const float4*>(x) + (size_t)q * 4;
    const float4* qy4 = reinterpret_cast<const float4*>(y) + (size_t)q * 4;
    #pragma unroll
    for (int i = 0; i < 4; ++i) {
        float4 v = qx4[i];
        qv[4*i+0] = v.x; qv[4*i+1] = v.y; qv[4*i+2] = v.z; qv[4*i+3] = v.w;
        float4 w = qy4[i];
        qv[16+4*i+0] = w.x; qv[16+4*i+1] = w.y; qv[16+4*i+2] = w.z; qv[16+4*i+3] = w.w;
    }
}

// ---------------------------------------------------------------------------
// K1: per-query partial top-4 of joint Chebyshev distance over a point split.
// grid = (NPTS/(TPB*QPL), S). QPL=4 queries/lane amortize each LDS point read.
// __launch_bounds__(TPB,1): qv[4][32]=128 VGPRs must allocate (512-reg cap);
// (TPB,2) made the allocator spill the query array to scratch (R5: 1.27 GB
// FETCH of spill traffic). Do NOT tighten this.
// ---------------------------------------------------------------------------
__global__ __launch_bounds__(TPB, 1) void knn_part_kernel(
    const float* __restrict__ x, const float* __restrict__ y,
    float4* __restrict__ part, int pps)
{
    __shared__ float4 pts4[TILE * 8];
    float qv[QPL][32];
    float t0[QPL], t1[QPL], t2[QPL], t3[QPL];
    #pragma unroll
    for (int u = 0; u < QPL; ++u) {
        load_query(qv[u], x, y, blockIdx.x * (TPB * QPL) + threadIdx.x + u * TPB);
        t0[u] = t1[u] = t2[u] = t3[u] = -1.0f;
    }

    const int j0 = blockIdx.y * pps;
    for (int jt = j0; jt < j0 + pps; jt += TILE) {
        stage_tile(pts4, x, y, jt);
        __syncthreads();
        #pragma unroll 2
        for (int jj = 0; jj < TILE; ++jj) {
            const float4* pj = &pts4[jj * 8];
            float m[QPL];
            #pragma unroll
            for (int u = 0; u < QPL; ++u) m[u] = 0.0f;   // distances >= 0
            #pragma unroll
            for (int i = 0; i < 8; ++i) {
                float4 v = pj[i];                         // wave-uniform broadcast
                #pragma unroll
                for (int u = 0; u < QPL; ++u) {
                    float d0 = qv[u][4*i+0] - v.x;
                    float d1 = qv[u][4*i+1] - v.y;
                    float d2 = qv[u][4*i+2] - v.z;
                    float d3 = qv[u][4*i+3] - v.w;
                    m[u] = fmax3(m[u], fmax3(fabsf(d0), fabsf(d1), fabsf(d2)), fabsf(d3));
                }
            }
            #pragma unroll
            for (int u = 0; u < QPL; ++u)
                ins4(m[u], t0[u], t1[u], t2[u], t3[u]);
        }
        __syncthreads();
    }
    #pragma unroll
    for (int u = 0; u < QPL; ++u) {
        int q = blockIdx.x * (TPB * QPL) + threadIdx.x + u * TPB;
        part[(size_t)blockIdx.y * NPTS + q] = make_float4(t0[u], t1[u], t2[u], t3[u]);
    }
}

// ---------------------------------------------------------------------------
// K2: merge S partial top-4 lists per query -> radius r[q]
// ---------------------------------------------------------------------------
__global__ __launch_bounds__(TPM) void knn_merge_kernel(
    const float4* __restrict__ part, float* __restrict__ r, int S)
{
    const int q = blockIdx.x * TPM + threadIdx.x;
    float t0=-1.f,t1=-1.f,t2=-1.f,t3=-1.f;
    for (int s = 0; s < S; ++s) {
        float4 v = part[(size_t)s * NPTS + q];
        ins4(v.x, t0, t1, t2, t3);
        ins4(v.y, t0, t1, t2, t3);
        ins4(v.z, t0, t1, t2, t3);
        ins4(v.w, t0, t1, t2, t3);
    }
    r[q] = t3 - 1e-15f;
}

// ---------------------------------------------------------------------------
// K3: partial inclusive range counts in X and Y marginals.
// ---------------------------------------------------------------------------
__global__ __launch_bounds__(TPB, 1) void count_part_kernel(
    const float* __restrict__ x, const float* __restrict__ y,
    const float* __restrict__ r,
    unsigned short* __restrict__ cx, unsigned short* __restrict__ cy, int pps)
{
    __shared__ float4 pts4[TILE * 8];
    float qv[QPL][32];
    float rq[QPL];
    int nx[QPL], ny[QPL];
    #pragma unroll
    for (int u = 0; u < QPL; ++u) {
        int q = blockIdx.x * (TPB * QPL) + threadIdx.x + u * TPB;
        load_query(qv[u], x, y, q);
        rq[u] = r[q];
        nx[u] = ny[u] = 0;
    }

    const int j0 = blockIdx.y * pps;
    for (int jt = j0; jt < j0 + pps; jt += TILE) {
        stage_tile(pts4, x, y, jt);
        __syncthreads();
        #pragma unroll 2
        for (int jj = 0; jj < TILE; ++jj) {
            const float4* pj = &pts4[jj * 8];
            float mx[QPL], my[QPL];
            #pragma unroll
            for (int u = 0; u < QPL; ++u) { mx[u] = 0.0f; my[u] = 0.0f; }
            #pragma unroll
            for (int i = 0; i < 8; ++i) {
                float4 v = pj[i];                         // wave-uniform broadcast
                #pragma unroll
                for (int u = 0; u < QPL; ++u) {
                    float d0 = qv[u][4*i+0] - v.x;
                    float d1 = qv[u][4*i+1] - v.y;
                    float d2 = qv[u][4*i+2] - v.z;
                    float d3 = qv[u][4*i+3] - v.w;
                    float t  = fmax3(fmax3(fabsf(d0), fabsf(d1), fabsf(d2)), fabsf(d3),
                                     (i < 4) ? mx[u] : my[u]);
                    if (i < 4) mx[u] = t; else my[u] = t;
                }
            }
            #pragma unroll
            for (int u = 0; u < QPL; ++u) {
                nx[u] += (mx[u] <= rq[u]) ? 1 : 0;
                ny[u] += (my[u] <= rq[u]) ? 1 : 0;
            }
        }
        __syncthreads();
    }
    #pragma unroll
    for (int u = 0; u < QPL; ++u) {
        int q = blockIdx.x * (TPB * QPL) + threadIdx.x + u * TPB;
        cx[(size_t)blockIdx.y * NPTS + q] = (unsigned short)nx[u];
        cy[(size_t)blockIdx.y * NPTS + q] = (unsigned short)ny[u];
    }
}

// ---------------------------------------------------------------------------
// K4: merge partial counts -> digamma(nx)+digamma(ny) per query (f64).
// ---------------------------------------------------------------------------
__global__ __launch_bounds__(TPM) void count_merge_kernel(
    const unsigned short* __restrict__ cx, const unsigned short* __restrict__ cy,
    double* __restrict__ dig, int S)
{
    const int q = blockIdx.x * TPM + threadIdx.x;
    int nx = 0, ny = 0;
    for (int s = 0; s < S; ++s) {
        nx += cx[(size_t)s * NPTS + q];
        ny += cy[(size_t)s * NPTS + q];
    }
    dig[q] = digamma_d((double)nx) + digamma_d((double)ny);
}

// ---------------------------------------------------------------------------
// K5: ans = psi(N) + psi(k) - mean(psi(nx)+psi(ny))
// (log/log2 terms of the reference cancel exactly in ans_x+ans_y-ans_xy)
// ---------------------------------------------------------------------------
__global__ __launch_bounds__(TPM) void final_kernel(
    const double* __restrict__ dig, float* __restrict__ out)
{
    __shared__ double sm[TPM];
    double s = 0.0;
    for (int i = threadIdx.x; i < NPTS; i += TPM) s += dig[i];
    sm[threadIdx.x] = s;
    __syncthreads();
    for (int w = TPM / 2; w > 0; w >>= 1) {
        if (threadIdx.x < w) sm[threadIdx.x] += sm[threadIdx.x + w];
        __syncthreads();
    }
    if (threadIdx.x == 0) {
        double ans = digamma_d((double)NPTS) + digamma_d(4.0) - sm[0] / (double)NPTS;
        out[0] = (float)ans;
    }
}

// ---------------------------------------------------------------------------
extern "C" void kernel_launch(void* const* d_in, const int* in_sizes, int n_in,
                              void* d_out, int out_size, void* d_ws, size_t ws_size,
                              hipStream_t stream)
{
    (void)in_sizes; (void)n_in; (void)out_size;
    const float* x = (const float*)d_in[0];
    const float* y = (const float*)d_in[1];
    float* out = (float*)d_out;

    // workspace: dig (NPTS f64) | r (NPTS f32) | part (Sk*NPTS float4) | cx,cy (Sc*NPTS u16 each)
    char* ws = (char*)d_ws;
    double* dig = (double*)ws;
    float*  r   = (float*)(ws + (size_t)NPTS * 8);
    char*   p0  = (char*)((((size_t)(ws + (size_t)NPTS * 12)) + 15) & ~(size_t)15);

    int Sk = 128, Sc = 128;
    auto need = [&](int sk, int sc) {
        return (size_t)(p0 - ws) + (size_t)sk * NPTS * 16 + (size_t)sc * NPTS * 4;
    };
    while (Sk > 32 && need(Sk, Sc) > ws_size) { Sk >>= 1; Sc >>= 1; }

    float4* part = (float4*)p0;
    unsigned short* cx = (unsigned short*)(p0 + (size_t)Sk * NPTS * 16);
    unsigned short* cy = cx + (size_t)Sc * NPTS;

    const int pps_k = NPTS / Sk;   // Sk<=128 -> >=64, multiple of TILE
    const int pps_c = NPTS / Sc;

    dim3 gridK(NPTS / (TPB * QPL), Sk);   // (16,128) = 2048 blocks = 8192 waves
    dim3 gridC(NPTS / (TPB * QPL), Sc);
    knn_part_kernel<<<gridK, TPB, 0, stream>>>(x, y, part, pps_k);
    knn_merge_kernel<<<NPTS / TPM, TPM, 0, stream>>>(part, r, Sk);
    count_part_kernel<<<gridC, TPB, 0, stream>>>(x, y, r, cx, cy, pps_c);
    count_merge_kernel<<<NPTS / TPM, TPM, 0, stream>>>(cx, cy, dig, Sc);
    final_kernel<<<1, TPM, 0, stream>>>(dig, out);
}